// Round 1
// baseline (220.049 us; speedup 1.0000x reference)
//
#include <hip/hip_runtime.h>
#include <math.h>

// Problem constants: B=1, H=8, S=512, D=64, P=32
#define HH 8
#define SS 512
#define DD 64
#define PP 32

__device__ __forceinline__ float softplusf(float x) {
    // jax.nn.softplus = log1p(exp(x)), stable for large x
    if (x > 20.f) return x;
    return log1pf(__expf(x));
}

// ---------------------------------------------------------------------------
// Kernel 1: per-token precompute.
//   role 0 (q): f_q[h,s] (2-layer ICNN), phi_q[h,s,p] = exp(q . Wh_p)
//   role 1 (k): g_k[h,s],                phi_k[h,s,p]
//   role 2 (v): u[h,s,p] = v . Wv_p
// One wave per token (lane j = feature j), 4 waves/block, 4 tokens/wave.
// Weights staged in LDS, transposed with padding to avoid bank conflicts.
// ---------------------------------------------------------------------------
__global__ __launch_bounds__(256) void csm_token_kernel(
    const float* __restrict__ q, const float* __restrict__ k, const float* __restrict__ v,
    const float* __restrict__ sq_raw1, const float* __restrict__ sq_b1,
    const float* __restrict__ sq_raw2, const float* __restrict__ sq_b2,
    const float* __restrict__ sk_raw1, const float* __restrict__ sk_b1,
    const float* __restrict__ sk_raw2, const float* __restrict__ sk_b2,
    const float* __restrict__ Wh, const float* __restrict__ Wv,
    float* __restrict__ fq, float* __restrict__ gk,
    float* __restrict__ phiq, float* __restrict__ phik, float* __restrict__ u)
{
    __shared__ float w1t[64 * 65];   // softplus(raw1) transposed, pad 65
    __shared__ float w2t[64 * 65];
    __shared__ float wht[64 * 33];   // Wh (or Wv) transposed, pad 33
    __shared__ float b1s[64], b2s[64];

    const int bx   = blockIdx.x;
    const int role = bx >> 8;        // 256 blocks per role
    const int grp  = bx & 255;       // 16 tokens per block
    const int tid  = threadIdx.x;
    const int wave = tid >> 6, lane = tid & 63;
    const int p    = lane & 31;

    if (role < 2) {
        const float* r1  = (role == 0) ? sq_raw1 : sk_raw1;
        const float* r2  = (role == 0) ? sq_raw2 : sk_raw2;
        const float* bb1 = (role == 0) ? sq_b1  : sk_b1;
        const float* bb2 = (role == 0) ? sq_b2  : sk_b2;
        for (int idx = tid; idx < 4096; idx += 256) {
            int j = idx >> 6, i = idx & 63;        // raw[j][i]
            w1t[i * 65 + j] = softplusf(r1[idx]);
            w2t[i * 65 + j] = softplusf(r2[idx]);
        }
        for (int idx = tid; idx < 2048; idx += 256) {
            int pp_ = idx >> 6, i = idx & 63;      // Wh[p][i]
            wht[i * 33 + pp_] = Wh[idx];
        }
        if (tid < 64) { b1s[tid] = bb1[tid]; b2s[tid] = bb2[tid]; }
    } else {
        for (int idx = tid; idx < 2048; idx += 256) {
            int pp_ = idx >> 6, i = idx & 63;      // Wv[p][i]
            wht[i * 33 + pp_] = Wv[idx];
        }
    }
    __syncthreads();

    const float* xin = (role == 0) ? q : ((role == 1) ? k : v);

    for (int tk = 0; tk < 4; ++tk) {
        const int g = grp * 16 + wave * 4 + tk;    // token index 0..4095 (h*512+s)
        const float x = xin[g * 64 + lane];

        if (role == 2) {
            float au = 0.f;
            #pragma unroll
            for (int i = 0; i < 64; ++i) {
                float xi = __shfl(x, i, 64);
                au += wht[i * 33 + p] * xi;
            }
            if (lane < 32) u[g * 32 + p] = au;
        } else {
            float a1 = b1s[lane], ah = 0.f;
            #pragma unroll
            for (int i = 0; i < 64; ++i) {
                float xi = __shfl(x, i, 64);
                a1 += w1t[i * 65 + lane] * xi;
                ah += wht[i * 33 + p] * xi;
            }
            float z1 = softplusf(a1);
            float a2 = b2s[lane];
            #pragma unroll
            for (int i = 0; i < 64; ++i) {
                float zi = __shfl(z1, i, 64);
                a2 += w2t[i * 65 + lane] * zi;
            }
            float z2 = softplusf(a2);
            float sum = z2;
            #pragma unroll
            for (int off = 32; off >= 1; off >>= 1)
                sum += __shfl_xor(sum, off, 64);
            if (role == 0) {
                if (lane == 0) fq[g] = sum;
                if (lane < 32) phiq[g * 32 + p] = __expf(ah);
            } else {
                if (lane == 0) gk[g] = sum;
                if (lane < 32) phik[g * 32 + p] = __expf(ah);
            }
        }
    }
}

// ---------------------------------------------------------------------------
// Kernel 2: per-head m2[p] = max_t u[t,p]; then u <- exp(u - m2) in place.
// One block per head.
// ---------------------------------------------------------------------------
__global__ __launch_bounds__(256) void csm_m2_kernel(
    float* __restrict__ u, float* __restrict__ m2)
{
    __shared__ float red[256];
    __shared__ float m2s[32];
    const int h = blockIdx.x;
    const int tid = threadIdx.x;
    const int p = tid & 31, chunk = tid >> 5;
    float* uh = u + h * SS * PP;

    float m = -INFINITY;
    for (int tt = 0; tt < 64; ++tt)
        m = fmaxf(m, uh[(chunk * 64 + tt) * 32 + p]);
    red[tid] = m;
    __syncthreads();
    if (tid < 32) {
        float mm = red[tid];
        #pragma unroll
        for (int c = 1; c < 8; ++c) mm = fmaxf(mm, red[c * 32 + tid]);
        m2[h * 32 + tid] = mm;
        m2s[tid] = mm;
    }
    __syncthreads();
    for (int idx = tid; idx < SS * PP; idx += 256)
        uh[idx] = __expf(uh[idx] - m2s[idx & 31]);
}

// ---------------------------------------------------------------------------
// Kernel 3: the S x S mixing without materializing it.
//   e[s,t] = g_k[t] + log( phi_q[s] . phi_k[t] )     (f_q drops out of softmax)
//   m[s]   = max_t e[s,t]
//   acc[s,p] = sum_t exp(e[s,t]-m[s]) * uexp[t,p]
//   y[s,p] = log(acc) + f_q[s] + m[s] + m2[p] - log(S)
// Block: 8 rows of one head, 4 waves x 2 rows. t processed in 4 tiles of 128
// staged through one shared LDS buffer (pass1: phi_k, pass2: uexp).
// Stride-33 padding -> all LDS access <=2-way (free).
// ---------------------------------------------------------------------------
#define TS 8
__global__ __launch_bounds__(256) void csm_mix_kernel(
    const float* __restrict__ fq, const float* __restrict__ gk,
    const float* __restrict__ phiq, const float* __restrict__ phik,
    const float* __restrict__ uexp, const float* __restrict__ m2,
    float* __restrict__ y)
{
    __shared__ float buf[128 * 33];      // 16.5 KB, shared pass1/pass2
    __shared__ float gks[SS];
    __shared__ float ws0_[4][128];
    __shared__ float ws1_[4][128];
    __shared__ float phiqs[TS * 32];
    __shared__ float fqs[TS];

    const int h   = blockIdx.y;
    const int s0  = blockIdx.x * TS;
    const int tid = threadIdx.x;
    const int wave = tid >> 6, lane = tid & 63;
    const int p = lane & 31, half = lane >> 5;

    const float* gkh = gk + h * SS;
    for (int i = tid; i < SS; i += 256) gks[i] = gkh[i];
    for (int i = tid; i < TS * 32; i += 256) phiqs[i] = phiq[(h * SS + s0) * 32 + i];
    if (tid < TS) fqs[tid] = fq[h * SS + s0 + tid];
    __syncthreads();

    const int rl0 = wave * 2, rl1 = wave * 2 + 1;
    float pq0[32], pq1[32];
    #pragma unroll
    for (int pp_ = 0; pp_ < 32; ++pp_) {
        pq0[pp_] = phiqs[rl0 * 32 + pp_];
        pq1[pp_] = phiqs[rl1 * 32 + pp_];
    }

    float e0[8], e1[8];
    const float* phikh = phik + h * SS * PP;

    // ---- pass 1: scores -> e, keep in registers ----
    #pragma unroll
    for (int tile = 0; tile < 4; ++tile) {
        const float4* src = (const float4*)(phikh + tile * 128 * 32);
        for (int idx4 = tid; idx4 < 1024; idx4 += 256) {
            float4 vv = src[idx4];
            int t = idx4 >> 3, pc = (idx4 & 7) * 4;
            float* dst = &buf[t * 33 + pc];
            dst[0] = vv.x; dst[1] = vv.y; dst[2] = vv.z; dst[3] = vv.w;
        }
        __syncthreads();
        #pragma unroll
        for (int jj = 0; jj < 2; ++jj) {
            const int tl = jj * 64 + lane;
            float s0v = 0.f, s1v = 0.f;
            #pragma unroll
            for (int pp_ = 0; pp_ < 32; ++pp_) {
                float bk = buf[tl * 33 + pp_];
                s0v += pq0[pp_] * bk;
                s1v += pq1[pp_] * bk;
            }
            const float gkt = gks[tile * 128 + tl];
            e0[tile * 2 + jj] = gkt + __logf(s0v);
            e1[tile * 2 + jj] = gkt + __logf(s1v);
        }
        __syncthreads();
    }

    // ---- row maxes ----
    float m0 = e0[0], m1v = e1[0];
    #pragma unroll
    for (int j = 1; j < 8; ++j) { m0 = fmaxf(m0, e0[j]); m1v = fmaxf(m1v, e1[j]); }
    #pragma unroll
    for (int off = 32; off >= 1; off >>= 1) {
        m0  = fmaxf(m0,  __shfl_xor(m0,  off, 64));
        m1v = fmaxf(m1v, __shfl_xor(m1v, off, 64));
    }

    // ---- pass 2: acc ----
    float acc0 = 0.f, acc1 = 0.f;
    const float* uh = uexp + h * SS * PP;
    #pragma unroll
    for (int tile = 0; tile < 4; ++tile) {
        const float4* src = (const float4*)(uh + tile * 128 * 32);
        for (int idx4 = tid; idx4 < 1024; idx4 += 256) {
            float4 vv = src[idx4];
            int t = idx4 >> 3, pc = (idx4 & 7) * 4;
            float* dst = &buf[t * 33 + pc];
            dst[0] = vv.x; dst[1] = vv.y; dst[2] = vv.z; dst[3] = vv.w;
        }
        __syncthreads();
        #pragma unroll
        for (int jj = 0; jj < 2; ++jj) {
            const int tl = jj * 64 + lane;
            ws0_[wave][tl] = __expf(e0[tile * 2 + jj] - m0);
            ws1_[wave][tl] = __expf(e1[tile * 2 + jj] - m1v);
        }
        __syncthreads();
        for (int tt = 0; tt < 64; ++tt) {
            const int tl = half * 64 + tt;
            const float up = buf[tl * 33 + p];
            acc0 += ws0_[wave][tl] * up;
            acc1 += ws1_[wave][tl] * up;
        }
        __syncthreads();
    }
    acc0 += __shfl_xor(acc0, 32, 64);
    acc1 += __shfl_xor(acc1, 32, 64);

    if (lane < 32) {
        const float LOG_S = 6.2383246250395078f;   // log(512)
        const float m2v = m2[h * 32 + p];
        y[(h * SS + s0 + rl0) * 32 + p] = __logf(acc0) + fqs[rl0] + m0  + m2v - LOG_S;
        y[(h * SS + s0 + rl1) * 32 + p] = __logf(acc1) + fqs[rl1] + m1v + m2v - LOG_S;
    }
}

extern "C" void kernel_launch(void* const* d_in, const int* in_sizes, int n_in,
                              void* d_out, int out_size, void* d_ws, size_t ws_size,
                              hipStream_t stream) {
    (void)in_sizes; (void)n_in; (void)out_size; (void)ws_size;
    const float* q       = (const float*)d_in[0];
    const float* k       = (const float*)d_in[1];
    const float* v       = (const float*)d_in[2];
    const float* sq_raw1 = (const float*)d_in[3];
    const float* sq_b1   = (const float*)d_in[4];
    const float* sq_raw2 = (const float*)d_in[5];
    const float* sq_b2   = (const float*)d_in[6];
    const float* sk_raw1 = (const float*)d_in[7];
    const float* sk_b1   = (const float*)d_in[8];
    const float* sk_raw2 = (const float*)d_in[9];
    const float* sk_b2   = (const float*)d_in[10];
    const float* Wh      = (const float*)d_in[11];
    const float* Wv      = (const float*)d_in[12];
    float* y = (float*)d_out;

    float* ws   = (float*)d_ws;
    float* fq   = ws;                 // 4096
    float* gk   = ws + 4096;          // 4096
    float* phiq = ws + 8192;          // 131072
    float* phik = ws + 139264;        // 131072
    float* u    = ws + 270336;        // 131072 (becomes exp(u-m2))
    float* m2   = ws + 401408;        // 256

    csm_token_kernel<<<768, 256, 0, stream>>>(
        q, k, v, sq_raw1, sq_b1, sq_raw2, sq_b2,
        sk_raw1, sk_b1, sk_raw2, sk_b2, Wh, Wv,
        fq, gk, phiq, phik, u);
    csm_m2_kernel<<<HH, 256, 0, stream>>>(u, m2);
    dim3 gridD(SS / TS, HH);
    csm_mix_kernel<<<gridD, 256, 0, stream>>>(fq, gk, phiq, phik, u, m2, y);
}

// Round 2
// 170.143 us; speedup vs baseline: 1.2933x; 1.2933x over previous
//
#include <hip/hip_runtime.h>
#include <math.h>

// Problem constants: B=1, H=8, S=512, D=64, P=32
#define HH 8
#define SS 512
#define DD 64
#define PP 32

__device__ __forceinline__ float softplusf(float x) {
    if (x > 20.f) return x;
    return log1pf(__expf(x));
}

// ---------------------------------------------------------------------------
// Kernel 0: one-time weight prep.
// wbuf layout (floats):
//   [0..4096)      w1qT : softplus(sq_raw1) transposed -> [i][j]
//   [4096..8192)   w2qT
//   [8192..12288)  w1kT
//   [12288..16384) w2kT
//   [16384..18432) whT  : Wh transposed -> [i][p]
//   [18432..20480) wvT  : Wv transposed -> [i][p]
// ---------------------------------------------------------------------------
__global__ __launch_bounds__(256) void csm_prep(
    const float* __restrict__ sq1, const float* __restrict__ sq2,
    const float* __restrict__ sk1, const float* __restrict__ sk2,
    const float* __restrict__ Wh, const float* __restrict__ Wv,
    float* __restrict__ wbuf)
{
    int idx = blockIdx.x * 256 + threadIdx.x;   // grid = 80 blocks -> 20480
    if (idx < 16384) {
        int m = idx >> 12, r = idx & 4095;
        int i = r >> 6, j = r & 63;             // dest [i][j] = softplus(src[j][i])
        const float* src = (m == 0) ? sq1 : (m == 1) ? sq2 : (m == 2) ? sk1 : sk2;
        wbuf[idx] = softplusf(src[j * 64 + i]);
    } else if (idx < 18432) {
        int r = idx - 16384; int i = r >> 5, p = r & 31;
        wbuf[idx] = Wh[p * 64 + i];
    } else if (idx < 20480) {
        int r = idx - 18432; int i = r >> 5, p = r & 31;
        wbuf[idx] = Wv[p * 64 + i];
    }
}

// ---------------------------------------------------------------------------
// Kernel 1: per-token compute, register-tiled GEMM.
// Grid 192 blocks: role = bx>>6 (0=q, 1=k, 2=v), 64 tokens/block.
// 256 threads = 16x16 (tr, tc); thread tile = 4 tokens x 4 outputs (or x2 for P).
// roles 0/1: z1 = sp(X@W1T+b1) fused with phi = exp(X@WhT); then z2, row-sum.
// role 2:    uexp = exp(X@WvT)   (m2 stabilizer dropped -- mathematically exact)
// ---------------------------------------------------------------------------
__global__ __launch_bounds__(256) void csm_token2(
    const float* __restrict__ q, const float* __restrict__ k, const float* __restrict__ v,
    const float* __restrict__ sq_b1, const float* __restrict__ sq_b2,
    const float* __restrict__ sk_b1, const float* __restrict__ sk_b2,
    const float* __restrict__ wbuf,
    float* __restrict__ fq, float* __restrict__ gk,
    float* __restrict__ phiq, float* __restrict__ phik, float* __restrict__ uexp)
{
    __shared__ float xs[64 * 68];     // X tile [t][i], later reused as z1 tile
    __shared__ float w1[64 * 68];     // W1T [i][j]
    __shared__ float w2[64 * 68];     // W2T [i][j]
    __shared__ float wh[64 * 36];     // WhT/WvT [i][p]
    __shared__ float part[64 * 17];   // row-sum partials
    __shared__ float bb1[64], bb2[64];

    const int bx   = blockIdx.x;
    const int role = bx >> 6;
    const int g0   = (bx & 63) * 64;
    const int tid  = threadIdx.x;
    const int tr = tid >> 4, tc = tid & 15;
    const int m0 = tr * 4, n0 = tc * 4, p0 = tc * 2;

    const float* xin = (role == 0) ? q : (role == 1) ? k : v;

    // ---- stage X tile ----
    const float4* xsrc = (const float4*)(xin + g0 * 64);
    #pragma unroll
    for (int c = 0; c < 4; ++c) {
        int idx4 = tid + c * 256;
        int t = idx4 >> 4, ic = (idx4 & 15) * 4;
        *(float4*)&xs[t * 68 + ic] = xsrc[idx4];
    }
    // ---- stage projection weights ----
    const float4* whsrc = (const float4*)(wbuf + ((role == 2) ? 18432 : 16384));
    #pragma unroll
    for (int c = 0; c < 2; ++c) {
        int idx4 = tid + c * 256;
        int i = idx4 >> 3, pc = (idx4 & 7) * 4;
        *(float4*)&wh[i * 36 + pc] = whsrc[idx4];
    }
    if (role < 2) {
        const float4* w1src = (const float4*)(wbuf + (role == 0 ? 0 : 8192));
        const float4* w2src = (const float4*)(wbuf + (role == 0 ? 4096 : 12288));
        #pragma unroll
        for (int c = 0; c < 4; ++c) {
            int idx4 = tid + c * 256;
            int i = idx4 >> 4, jc = (idx4 & 15) * 4;
            *(float4*)&w1[i * 68 + jc] = w1src[idx4];
            *(float4*)&w2[i * 68 + jc] = w2src[idx4];
        }
        if (tid < 64) {
            bb1[tid] = (role == 0 ? sq_b1 : sk_b1)[tid];
            bb2[tid] = (role == 0 ? sq_b2 : sk_b2)[tid];
        }
    }
    __syncthreads();

    if (role == 2) {
        // u = v @ WvT, store exp(u)
        float acc[4][2] = {{0.f,0.f},{0.f,0.f},{0.f,0.f},{0.f,0.f}};
        #pragma unroll
        for (int kc = 0; kc < 16; ++kc) {
            const int i0 = kc * 4;
            float4 xv[4]; float2 hv[4];
            #pragma unroll
            for (int mm = 0; mm < 4; ++mm) xv[mm] = *(const float4*)&xs[(m0 + mm) * 68 + i0];
            #pragma unroll
            for (int kk = 0; kk < 4; ++kk) hv[kk] = *(const float2*)&wh[(i0 + kk) * 36 + p0];
            #pragma unroll
            for (int mm = 0; mm < 4; ++mm) {
                const float* xa = (const float*)&xv[mm];
                #pragma unroll
                for (int kk = 0; kk < 4; ++kk) {
                    acc[mm][0] += xa[kk] * hv[kk].x;
                    acc[mm][1] += xa[kk] * hv[kk].y;
                }
            }
        }
        #pragma unroll
        for (int mm = 0; mm < 4; ++mm) {
            float2 o; o.x = __expf(acc[mm][0]); o.y = __expf(acc[mm][1]);
            *(float2*)&uexp[(g0 + m0 + mm) * 32 + p0] = o;
        }
        return;   // uniform per block -- no barrier divergence
    }

    // ---- roles 0/1: layer1 + phi fused ----
    float acc[4][4], accp[4][2];
    #pragma unroll
    for (int mm = 0; mm < 4; ++mm) {
        #pragma unroll
        for (int j = 0; j < 4; ++j) acc[mm][j] = bb1[n0 + j];
        accp[mm][0] = 0.f; accp[mm][1] = 0.f;
    }
    #pragma unroll
    for (int kc = 0; kc < 16; ++kc) {
        const int i0 = kc * 4;
        float4 xv[4], wv[4]; float2 hv[4];
        #pragma unroll
        for (int mm = 0; mm < 4; ++mm) xv[mm] = *(const float4*)&xs[(m0 + mm) * 68 + i0];
        #pragma unroll
        for (int kk = 0; kk < 4; ++kk) {
            wv[kk] = *(const float4*)&w1[(i0 + kk) * 68 + n0];
            hv[kk] = *(const float2*)&wh[(i0 + kk) * 36 + p0];
        }
        #pragma unroll
        for (int mm = 0; mm < 4; ++mm) {
            const float* xa = (const float*)&xv[mm];
            #pragma unroll
            for (int kk = 0; kk < 4; ++kk) {
                const float xmk = xa[kk];
                const float* wa = (const float*)&wv[kk];
                acc[mm][0] += xmk * wa[0];
                acc[mm][1] += xmk * wa[1];
                acc[mm][2] += xmk * wa[2];
                acc[mm][3] += xmk * wa[3];
                accp[mm][0] += xmk * hv[kk].x;
                accp[mm][1] += xmk * hv[kk].y;
            }
        }
    }
    // phi output
    float* phiout = (role == 0) ? phiq : phik;
    #pragma unroll
    for (int mm = 0; mm < 4; ++mm) {
        float2 o; o.x = __expf(accp[mm][0]); o.y = __expf(accp[mm][1]);
        *(float2*)&phiout[(g0 + m0 + mm) * 32 + p0] = o;
    }
    // z1 = softplus(acc) -> overwrite xs
    float z1v[4][4];
    #pragma unroll
    for (int mm = 0; mm < 4; ++mm)
        #pragma unroll
        for (int j = 0; j < 4; ++j) z1v[mm][j] = softplusf(acc[mm][j]);
    __syncthreads();
    #pragma unroll
    for (int mm = 0; mm < 4; ++mm)
        *(float4*)&xs[(m0 + mm) * 68 + n0] = *(float4*)&z1v[mm][0];
    __syncthreads();

    // ---- layer 2 ----
    float acc2[4][4];
    #pragma unroll
    for (int mm = 0; mm < 4; ++mm)
        #pragma unroll
        for (int j = 0; j < 4; ++j) acc2[mm][j] = bb2[n0 + j];
    #pragma unroll
    for (int kc = 0; kc < 16; ++kc) {
        const int i0 = kc * 4;
        float4 xv[4], wv[4];
        #pragma unroll
        for (int mm = 0; mm < 4; ++mm) xv[mm] = *(const float4*)&xs[(m0 + mm) * 68 + i0];
        #pragma unroll
        for (int kk = 0; kk < 4; ++kk) wv[kk] = *(const float4*)&w2[(i0 + kk) * 68 + n0];
        #pragma unroll
        for (int mm = 0; mm < 4; ++mm) {
            const float* xa = (const float*)&xv[mm];
            #pragma unroll
            for (int kk = 0; kk < 4; ++kk) {
                const float xmk = xa[kk];
                const float* wa = (const float*)&wv[kk];
                acc2[mm][0] += xmk * wa[0];
                acc2[mm][1] += xmk * wa[1];
                acc2[mm][2] += xmk * wa[2];
                acc2[mm][3] += xmk * wa[3];
            }
        }
    }
    // row sums of softplus(acc2)
    #pragma unroll
    for (int mm = 0; mm < 4; ++mm) {
        float s = softplusf(acc2[mm][0]) + softplusf(acc2[mm][1])
                + softplusf(acc2[mm][2]) + softplusf(acc2[mm][3]);
        part[(m0 + mm) * 17 + tc] = s;
    }
    __syncthreads();
    if (tid < 64) {
        float s = 0.f;
        #pragma unroll
        for (int c = 0; c < 16; ++c) s += part[tid * 17 + c];
        ((role == 0) ? fq : gk)[g0 + tid] = s;
    }
}

// ---------------------------------------------------------------------------
// Kernel 2: the S x S mixing without materializing it.
//   e[s,t] = g_k[t] + log( phi_q[s] . phi_k[t] )     (f_q drops out of softmax)
//   m[s]   = max_t e[s,t]
//   acc[s,p] = sum_t exp(e[s,t]-m[s]) * uexp[t,p]    (uexp = exp(u), m2 == 0)
//   y[s,p] = log(acc) + f_q[s] + m[s] - log(S)
// ---------------------------------------------------------------------------
#define TS 8
__global__ __launch_bounds__(256) void csm_mix_kernel(
    const float* __restrict__ fq, const float* __restrict__ gk,
    const float* __restrict__ phiq, const float* __restrict__ phik,
    const float* __restrict__ uexp, float* __restrict__ y)
{
    __shared__ float buf[128 * 33];      // 16.5 KB, shared pass1/pass2
    __shared__ float gks[SS];
    __shared__ float ws0_[4][128];
    __shared__ float ws1_[4][128];
    __shared__ float phiqs[TS * 32];
    __shared__ float fqs[TS];

    const int h   = blockIdx.y;
    const int s0  = blockIdx.x * TS;
    const int tid = threadIdx.x;
    const int wave = tid >> 6, lane = tid & 63;
    const int p = lane & 31, half = lane >> 5;

    const float* gkh = gk + h * SS;
    for (int i = tid; i < SS; i += 256) gks[i] = gkh[i];
    for (int i = tid; i < TS * 32; i += 256) phiqs[i] = phiq[(h * SS + s0) * 32 + i];
    if (tid < TS) fqs[tid] = fq[h * SS + s0 + tid];
    __syncthreads();

    const int rl0 = wave * 2, rl1 = wave * 2 + 1;
    float pq0[32], pq1[32];
    #pragma unroll
    for (int pp_ = 0; pp_ < 32; ++pp_) {
        pq0[pp_] = phiqs[rl0 * 32 + pp_];
        pq1[pp_] = phiqs[rl1 * 32 + pp_];
    }

    float e0[8], e1[8];
    const float* phikh = phik + h * SS * PP;

    // ---- pass 1: scores -> e, keep in registers ----
    #pragma unroll
    for (int tile = 0; tile < 4; ++tile) {
        const float4* src = (const float4*)(phikh + tile * 128 * 32);
        for (int idx4 = tid; idx4 < 1024; idx4 += 256) {
            float4 vv = src[idx4];
            int t = idx4 >> 3, pc = (idx4 & 7) * 4;
            float* dst = &buf[t * 33 + pc];
            dst[0] = vv.x; dst[1] = vv.y; dst[2] = vv.z; dst[3] = vv.w;
        }
        __syncthreads();
        #pragma unroll
        for (int jj = 0; jj < 2; ++jj) {
            const int tl = jj * 64 + lane;
            float s0v = 0.f, s1v = 0.f;
            #pragma unroll
            for (int pp_ = 0; pp_ < 32; ++pp_) {
                float bk = buf[tl * 33 + pp_];
                s0v += pq0[pp_] * bk;
                s1v += pq1[pp_] * bk;
            }
            const float gkt = gks[tile * 128 + tl];
            e0[tile * 2 + jj] = gkt + __logf(s0v);
            e1[tile * 2 + jj] = gkt + __logf(s1v);
        }
        __syncthreads();
    }

    // ---- row maxes ----
    float m0 = e0[0], m1v = e1[0];
    #pragma unroll
    for (int j = 1; j < 8; ++j) { m0 = fmaxf(m0, e0[j]); m1v = fmaxf(m1v, e1[j]); }
    #pragma unroll
    for (int off = 32; off >= 1; off >>= 1) {
        m0  = fmaxf(m0,  __shfl_xor(m0,  off, 64));
        m1v = fmaxf(m1v, __shfl_xor(m1v, off, 64));
    }

    // ---- pass 2: acc ----
    float acc0 = 0.f, acc1 = 0.f;
    const float* uh = uexp + h * SS * PP;
    #pragma unroll
    for (int tile = 0; tile < 4; ++tile) {
        const float4* src = (const float4*)(uh + tile * 128 * 32);
        for (int idx4 = tid; idx4 < 1024; idx4 += 256) {
            float4 vv = src[idx4];
            int t = idx4 >> 3, pc = (idx4 & 7) * 4;
            float* dst = &buf[t * 33 + pc];
            dst[0] = vv.x; dst[1] = vv.y; dst[2] = vv.z; dst[3] = vv.w;
        }
        __syncthreads();
        #pragma unroll
        for (int jj = 0; jj < 2; ++jj) {
            const int tl = jj * 64 + lane;
            ws0_[wave][tl] = __expf(e0[tile * 2 + jj] - m0);
            ws1_[wave][tl] = __expf(e1[tile * 2 + jj] - m1v);
        }
        __syncthreads();
        for (int tt = 0; tt < 64; ++tt) {
            const int tl = half * 64 + tt;
            const float up = buf[tl * 33 + p];
            acc0 += ws0_[wave][tl] * up;
            acc1 += ws1_[wave][tl] * up;
        }
        __syncthreads();
    }
    acc0 += __shfl_xor(acc0, 32, 64);
    acc1 += __shfl_xor(acc1, 32, 64);

    if (lane < 32) {
        const float LOG_S = 6.2383246250395078f;   // log(512)
        y[(h * SS + s0 + rl0) * 32 + p] = __logf(acc0) + fqs[rl0] + m0  - LOG_S;
        y[(h * SS + s0 + rl1) * 32 + p] = __logf(acc1) + fqs[rl1] + m1v - LOG_S;
    }
}

extern "C" void kernel_launch(void* const* d_in, const int* in_sizes, int n_in,
                              void* d_out, int out_size, void* d_ws, size_t ws_size,
                              hipStream_t stream) {
    (void)in_sizes; (void)n_in; (void)out_size; (void)ws_size;
    const float* q       = (const float*)d_in[0];
    const float* k       = (const float*)d_in[1];
    const float* v       = (const float*)d_in[2];
    const float* sq_raw1 = (const float*)d_in[3];
    const float* sq_b1   = (const float*)d_in[4];
    const float* sq_raw2 = (const float*)d_in[5];
    const float* sq_b2   = (const float*)d_in[6];
    const float* sk_raw1 = (const float*)d_in[7];
    const float* sk_b1   = (const float*)d_in[8];
    const float* sk_raw2 = (const float*)d_in[9];
    const float* sk_b2   = (const float*)d_in[10];
    const float* Wh      = (const float*)d_in[11];
    const float* Wv      = (const float*)d_in[12];
    float* y = (float*)d_out;

    float* ws   = (float*)d_ws;
    float* wbuf = ws;                  // 20480
    float* fq   = ws + 20480;          // 4096
    float* gk   = ws + 24576;          // 4096
    float* phiq = ws + 28672;          // 131072
    float* phik = ws + 159744;         // 131072
    float* uexp = ws + 290816;         // 131072

    csm_prep<<<80, 256, 0, stream>>>(sq_raw1, sq_raw2, sk_raw1, sk_raw2, Wh, Wv, wbuf);
    csm_token2<<<192, 256, 0, stream>>>(q, k, v, sq_b1, sq_b2, sk_b1, sk_b2,
                                        wbuf, fq, gk, phiq, phik, uexp);
    dim3 gridD(SS / TS, HH);
    csm_mix_kernel<<<gridD, 256, 0, stream>>>(fq, gk, phiq, phik, uexp, y);
}

// Round 3
// 131.480 us; speedup vs baseline: 1.6736x; 1.2941x over previous
//
#include <hip/hip_runtime.h>
#include <math.h>

// Problem constants: B=1, H=8, S=512, D=64, P=32
#define HH 8
#define SS 512
#define DD 64
#define PP 32

__device__ __forceinline__ float softplusf(float x) {
    if (x > 20.f) return x;
    return log1pf(__expf(x));
}

// ---------------------------------------------------------------------------
// Kernel 0: one-time weight prep (softplus + transpose into wbuf).
//   [0..4096)      w1qT   [4096..8192)  w2qT
//   [8192..12288)  w1kT   [12288..16384) w2kT
//   [16384..18432) whT    [18432..20480) wvT
// ---------------------------------------------------------------------------
__global__ __launch_bounds__(256) void csm_prep(
    const float* __restrict__ sq1, const float* __restrict__ sq2,
    const float* __restrict__ sk1, const float* __restrict__ sk2,
    const float* __restrict__ Wh, const float* __restrict__ Wv,
    float* __restrict__ wbuf)
{
    int idx = blockIdx.x * 256 + threadIdx.x;   // grid = 80 blocks -> 20480
    if (idx < 16384) {
        int m = idx >> 12, r = idx & 4095;
        int i = r >> 6, j = r & 63;             // dest [i][j] = softplus(src[j][i])
        const float* src = (m == 0) ? sq1 : (m == 1) ? sq2 : (m == 2) ? sk1 : sk2;
        wbuf[idx] = softplusf(src[j * 64 + i]);
    } else if (idx < 18432) {
        int r = idx - 16384; int i = r >> 5, p = r & 31;
        wbuf[idx] = Wh[p * 64 + i];
    } else if (idx < 20480) {
        int r = idx - 18432; int i = r >> 5, p = r & 31;
        wbuf[idx] = Wv[p * 64 + i];
    }
}

// ---------------------------------------------------------------------------
// Kernel 1: per-token compute, register-tiled GEMM (unchanged from R2).
// role 0 (q): fq, phiq   role 1 (k): gk, phik   role 2 (v): uexp = exp(v@WvT)
// ---------------------------------------------------------------------------
__global__ __launch_bounds__(256) void csm_token2(
    const float* __restrict__ q, const float* __restrict__ k, const float* __restrict__ v,
    const float* __restrict__ sq_b1, const float* __restrict__ sq_b2,
    const float* __restrict__ sk_b1, const float* __restrict__ sk_b2,
    const float* __restrict__ wbuf,
    float* __restrict__ fq, float* __restrict__ gk,
    float* __restrict__ phiq, float* __restrict__ phik, float* __restrict__ uexp)
{
    __shared__ float xs[64 * 68];
    __shared__ float w1[64 * 68];
    __shared__ float w2[64 * 68];
    __shared__ float wh[64 * 36];
    __shared__ float part[64 * 17];
    __shared__ float bb1[64], bb2[64];

    const int bx   = blockIdx.x;
    const int role = bx >> 6;
    const int g0   = (bx & 63) * 64;
    const int tid  = threadIdx.x;
    const int tr = tid >> 4, tc = tid & 15;
    const int m0 = tr * 4, n0 = tc * 4, p0 = tc * 2;

    const float* xin = (role == 0) ? q : (role == 1) ? k : v;

    const float4* xsrc = (const float4*)(xin + g0 * 64);
    #pragma unroll
    for (int c = 0; c < 4; ++c) {
        int idx4 = tid + c * 256;
        int t = idx4 >> 4, ic = (idx4 & 15) * 4;
        *(float4*)&xs[t * 68 + ic] = xsrc[idx4];
    }
    const float4* whsrc = (const float4*)(wbuf + ((role == 2) ? 18432 : 16384));
    #pragma unroll
    for (int c = 0; c < 2; ++c) {
        int idx4 = tid + c * 256;
        int i = idx4 >> 3, pc = (idx4 & 7) * 4;
        *(float4*)&wh[i * 36 + pc] = whsrc[idx4];
    }
    if (role < 2) {
        const float4* w1src = (const float4*)(wbuf + (role == 0 ? 0 : 8192));
        const float4* w2src = (const float4*)(wbuf + (role == 0 ? 4096 : 12288));
        #pragma unroll
        for (int c = 0; c < 4; ++c) {
            int idx4 = tid + c * 256;
            int i = idx4 >> 4, jc = (idx4 & 15) * 4;
            *(float4*)&w1[i * 68 + jc] = w1src[idx4];
            *(float4*)&w2[i * 68 + jc] = w2src[idx4];
        }
        if (tid < 64) {
            bb1[tid] = (role == 0 ? sq_b1 : sk_b1)[tid];
            bb2[tid] = (role == 0 ? sq_b2 : sk_b2)[tid];
        }
    }
    __syncthreads();

    if (role == 2) {
        float acc[4][2] = {{0.f,0.f},{0.f,0.f},{0.f,0.f},{0.f,0.f}};
        #pragma unroll
        for (int kc = 0; kc < 16; ++kc) {
            const int i0 = kc * 4;
            float4 xv[4]; float2 hv[4];
            #pragma unroll
            for (int mm = 0; mm < 4; ++mm) xv[mm] = *(const float4*)&xs[(m0 + mm) * 68 + i0];
            #pragma unroll
            for (int kk = 0; kk < 4; ++kk) hv[kk] = *(const float2*)&wh[(i0 + kk) * 36 + p0];
            #pragma unroll
            for (int mm = 0; mm < 4; ++mm) {
                const float* xa = (const float*)&xv[mm];
                #pragma unroll
                for (int kk = 0; kk < 4; ++kk) {
                    acc[mm][0] += xa[kk] * hv[kk].x;
                    acc[mm][1] += xa[kk] * hv[kk].y;
                }
            }
        }
        #pragma unroll
        for (int mm = 0; mm < 4; ++mm) {
            float2 o; o.x = __expf(acc[mm][0]); o.y = __expf(acc[mm][1]);
            *(float2*)&uexp[(g0 + m0 + mm) * 32 + p0] = o;
        }
        return;
    }

    float acc[4][4], accp[4][2];
    #pragma unroll
    for (int mm = 0; mm < 4; ++mm) {
        #pragma unroll
        for (int j = 0; j < 4; ++j) acc[mm][j] = bb1[n0 + j];
        accp[mm][0] = 0.f; accp[mm][1] = 0.f;
    }
    #pragma unroll
    for (int kc = 0; kc < 16; ++kc) {
        const int i0 = kc * 4;
        float4 xv[4], wv[4]; float2 hv[4];
        #pragma unroll
        for (int mm = 0; mm < 4; ++mm) xv[mm] = *(const float4*)&xs[(m0 + mm) * 68 + i0];
        #pragma unroll
        for (int kk = 0; kk < 4; ++kk) {
            wv[kk] = *(const float4*)&w1[(i0 + kk) * 68 + n0];
            hv[kk] = *(const float2*)&wh[(i0 + kk) * 36 + p0];
        }
        #pragma unroll
        for (int mm = 0; mm < 4; ++mm) {
            const float* xa = (const float*)&xv[mm];
            #pragma unroll
            for (int kk = 0; kk < 4; ++kk) {
                const float xmk = xa[kk];
                const float* wa = (const float*)&wv[kk];
                acc[mm][0] += xmk * wa[0];
                acc[mm][1] += xmk * wa[1];
                acc[mm][2] += xmk * wa[2];
                acc[mm][3] += xmk * wa[3];
                accp[mm][0] += xmk * hv[kk].x;
                accp[mm][1] += xmk * hv[kk].y;
            }
        }
    }
    float* phiout = (role == 0) ? phiq : phik;
    #pragma unroll
    for (int mm = 0; mm < 4; ++mm) {
        float2 o; o.x = __expf(accp[mm][0]); o.y = __expf(accp[mm][1]);
        *(float2*)&phiout[(g0 + m0 + mm) * 32 + p0] = o;
    }
    float z1v[4][4];
    #pragma unroll
    for (int mm = 0; mm < 4; ++mm)
        #pragma unroll
        for (int j = 0; j < 4; ++j) z1v[mm][j] = softplusf(acc[mm][j]);
    __syncthreads();
    #pragma unroll
    for (int mm = 0; mm < 4; ++mm)
        *(float4*)&xs[(m0 + mm) * 68 + n0] = *(float4*)&z1v[mm][0];
    __syncthreads();

    float acc2[4][4];
    #pragma unroll
    for (int mm = 0; mm < 4; ++mm)
        #pragma unroll
        for (int j = 0; j < 4; ++j) acc2[mm][j] = bb2[n0 + j];
    #pragma unroll
    for (int kc = 0; kc < 16; ++kc) {
        const int i0 = kc * 4;
        float4 xv[4], wv[4];
        #pragma unroll
        for (int mm = 0; mm < 4; ++mm) xv[mm] = *(const float4*)&xs[(m0 + mm) * 68 + i0];
        #pragma unroll
        for (int kk = 0; kk < 4; ++kk) wv[kk] = *(const float4*)&w2[(i0 + kk) * 68 + n0];
        #pragma unroll
        for (int mm = 0; mm < 4; ++mm) {
            const float* xa = (const float*)&xv[mm];
            #pragma unroll
            for (int kk = 0; kk < 4; ++kk) {
                const float xmk = xa[kk];
                const float* wa = (const float*)&wv[kk];
                acc2[mm][0] += xmk * wa[0];
                acc2[mm][1] += xmk * wa[1];
                acc2[mm][2] += xmk * wa[2];
                acc2[mm][3] += xmk * wa[3];
            }
        }
    }
    #pragma unroll
    for (int mm = 0; mm < 4; ++mm) {
        float s = softplusf(acc2[mm][0]) + softplusf(acc2[mm][1])
                + softplusf(acc2[mm][2]) + softplusf(acc2[mm][3]);
        part[(m0 + mm) * 17 + tc] = s;
    }
    __syncthreads();
    if (tid < 64) {
        float s = 0.f;
        #pragma unroll
        for (int c = 0; c < 16; ++c) s += part[tid * 17 + c];
        ((role == 0) ? fq : gk)[g0 + tid] = s;
    }
}

// ---------------------------------------------------------------------------
// Kernel 2: per-head factorized reduction.
//   G = max_t gk[h,t];  w[t] = exp(gk[t]-G)
//   M[r][p] = sum_t phik[t,r] * w[t] * uexp[t,p]     (32x32 per head)
// Grid = 8 blocks (one per head), 256 threads.
// Thread (r0 = (tid>>5)*4, p = tid&31) accumulates M[r0..r0+3][p].
// pk padded to 36 -> b128 reads, broadcast across lanes; wu reads stride-1.
// ---------------------------------------------------------------------------
__global__ __launch_bounds__(256) void csm_reduceM(
    const float* __restrict__ gk, const float* __restrict__ phik,
    const float* __restrict__ uexp,
    float* __restrict__ Mbuf, float* __restrict__ Gbuf)
{
    __shared__ float red[256];
    __shared__ float wls[SS];
    __shared__ float pk[128 * 36];
    __shared__ float wu[128 * 36];

    const int h = blockIdx.x;
    const int tid = threadIdx.x;
    const float* gkh = gk + h * SS;

    red[tid] = fmaxf(gkh[tid], gkh[tid + 256]);
    __syncthreads();
    for (int s = 128; s >= 1; s >>= 1) {
        if (tid < s) red[tid] = fmaxf(red[tid], red[tid + s]);
        __syncthreads();
    }
    const float G = red[0];
    if (tid == 0) Gbuf[h] = G;
    wls[tid]       = __expf(gkh[tid] - G);
    wls[tid + 256] = __expf(gkh[tid + 256] - G);
    __syncthreads();

    const int r0 = (tid >> 5) * 4, p = tid & 31;
    float macc[4] = {0.f, 0.f, 0.f, 0.f};
    const float* phikh = phik + h * SS * PP;
    const float* uh    = uexp + h * SS * PP;

    #pragma unroll
    for (int tile = 0; tile < 4; ++tile) {
        const float4* psrc = (const float4*)(phikh + tile * 128 * 32);
        const float4* usrc = (const float4*)(uh    + tile * 128 * 32);
        #pragma unroll
        for (int c = 0; c < 4; ++c) {
            int idx4 = tid + c * 256;
            int t = idx4 >> 3, pc = (idx4 & 7) * 4;
            *(float4*)&pk[t * 36 + pc] = psrc[idx4];
            float4 uv = usrc[idx4];
            float w = wls[tile * 128 + t];
            uv.x *= w; uv.y *= w; uv.z *= w; uv.w *= w;
            *(float4*)&wu[t * 36 + pc] = uv;
        }
        __syncthreads();
        for (int t = 0; t < 128; ++t) {
            const float wup = wu[t * 36 + p];
            const float4 pv = *(const float4*)&pk[t * 36 + r0];
            macc[0] += pv.x * wup;
            macc[1] += pv.y * wup;
            macc[2] += pv.z * wup;
            macc[3] += pv.w * wup;
        }
        __syncthreads();
    }
    #pragma unroll
    for (int rr = 0; rr < 4; ++rr)
        Mbuf[h * 1024 + (r0 + rr) * 32 + p] = macc[rr];
}

// ---------------------------------------------------------------------------
// Kernel 3: output.  y[s,p] = log( phi_q[s] . M[:,p] ) + f_q[s] + G - log S
// Grid = 512 blocks x 256 threads; block = 8 consecutive tokens x 32 p.
// ---------------------------------------------------------------------------
__global__ __launch_bounds__(256) void csm_out(
    const float* __restrict__ fq, const float* __restrict__ phiq,
    const float* __restrict__ Mbuf, const float* __restrict__ Gbuf,
    float* __restrict__ y)
{
    __shared__ float Ms[32 * 36];
    __shared__ float pqs[8 * 32];
    __shared__ float fqs[8];

    const int bx = blockIdx.x;
    const int s0 = bx * 8;           // global token index (h*512+s)
    const int h  = bx >> 6;
    const int tid = threadIdx.x;

    #pragma unroll
    for (int c = 0; c < 4; ++c) {
        int idx = tid + c * 256;
        Ms[(idx >> 5) * 36 + (idx & 31)] = Mbuf[h * 1024 + idx];
    }
    pqs[tid] = phiq[s0 * 32 + tid];
    if (tid < 8) fqs[tid] = fq[s0 + tid];
    __syncthreads();

    const int si = tid >> 5, p = tid & 31;
    float acc = 0.f;
    #pragma unroll
    for (int rc = 0; rc < 8; ++rc) {
        const float4 pq = *(const float4*)&pqs[si * 32 + rc * 4];
        acc += pq.x * Ms[(rc * 4 + 0) * 36 + p];
        acc += pq.y * Ms[(rc * 4 + 1) * 36 + p];
        acc += pq.z * Ms[(rc * 4 + 2) * 36 + p];
        acc += pq.w * Ms[(rc * 4 + 3) * 36 + p];
    }
    const float LOG_S = 6.2383246250395078f;   // log(512)
    y[(s0 + si) * 32 + p] = __logf(acc) + fqs[si] + Gbuf[h] - LOG_S;
}

extern "C" void kernel_launch(void* const* d_in, const int* in_sizes, int n_in,
                              void* d_out, int out_size, void* d_ws, size_t ws_size,
                              hipStream_t stream) {
    (void)in_sizes; (void)n_in; (void)out_size; (void)ws_size;
    const float* q       = (const float*)d_in[0];
    const float* k       = (const float*)d_in[1];
    const float* v       = (const float*)d_in[2];
    const float* sq_raw1 = (const float*)d_in[3];
    const float* sq_b1   = (const float*)d_in[4];
    const float* sq_raw2 = (const float*)d_in[5];
    const float* sq_b2   = (const float*)d_in[6];
    const float* sk_raw1 = (const float*)d_in[7];
    const float* sk_b1   = (const float*)d_in[8];
    const float* sk_raw2 = (const float*)d_in[9];
    const float* sk_b2   = (const float*)d_in[10];
    const float* Wh      = (const float*)d_in[11];
    const float* Wv      = (const float*)d_in[12];
    float* y = (float*)d_out;

    float* ws   = (float*)d_ws;
    float* wbuf = ws;                  // 20480
    float* fq   = ws + 20480;          // 4096
    float* gk   = ws + 24576;          // 4096
    float* phiq = ws + 28672;          // 131072
    float* phik = ws + 159744;         // 131072
    float* uexp = ws + 290816;         // 131072
    float* Mbuf = ws + 421888;         // 8192
    float* Gbuf = ws + 430080;         // 8

    csm_prep<<<80, 256, 0, stream>>>(sq_raw1, sq_raw2, sk_raw1, sk_raw2, Wh, Wv, wbuf);
    csm_token2<<<192, 256, 0, stream>>>(q, k, v, sq_b1, sq_b2, sk_b1, sk_b2,
                                        wbuf, fq, gk, phiq, phik, uexp);
    csm_reduceM<<<HH, 256, 0, stream>>>(gk, phik, uexp, Mbuf, Gbuf);
    csm_out<<<512, 256, 0, stream>>>(fq, phiq, Mbuf, Gbuf, y);
}